// Round 5
// baseline (6423.091 us; speedup 1.0000x reference)
//
#include <hip/hip_runtime.h>
#include <hip/hip_bf16.h>

typedef unsigned short u16;
typedef short bf16x8 __attribute__((ext_vector_type(8)));   // 8 bf16 (4 VGPRs) MFMA frag
typedef float floatx4 __attribute__((ext_vector_type(4)));  // MFMA acc

#define B_DIM 2048
#define F_DIM 4096
#define H_DIM 1024
#define NSTEP 64

__device__ __forceinline__ float fast_tanh(float x) {
    return 1.0f - 2.0f / (__expf(2.0f * x) + 1.0f);
}

__device__ __forceinline__ u16 f2b(float x) {  // fp32 -> bf16 RNE
    union { float f; unsigned u; } v; v.f = x;
    unsigned r = v.u + 0x7FFFu + ((v.u >> 16) & 1u);
    return (u16)(r >> 16);
}

template<int F32>
__device__ __forceinline__ int4 ld8(const void* base, size_t elemOff) {
    if constexpr (F32) {
        const float* p = (const float*)base + elemOff;
        float4 lo = *(const float4*)p;
        float4 hi = *(const float4*)(p + 4);
        union { u16 h[8]; int4 v; } rr;
        rr.h[0] = f2b(lo.x); rr.h[1] = f2b(lo.y); rr.h[2] = f2b(lo.z); rr.h[3] = f2b(lo.w);
        rr.h[4] = f2b(hi.x); rr.h[5] = f2b(hi.y); rr.h[6] = f2b(hi.z); rr.h[7] = f2b(hi.w);
        return rr.v;
    } else {
        return *(const int4*)((const u16*)base + elemOff);
    }
}

// ---------------- batched/selector GEMM for the parallel (MLP/pre) phase ----------------
// C[z] = act(A[z] @ W[z]^T + bias1[z]); grid must be (16, 32, z). BM=BN=BK=64.
// XCD swizzle: lin%8 == m-tile%8 -> A row-panels pinned per XCD L2.
template<int AF32, int WF32, int ACT, int OUT_F32>
__global__ __launch_bounds__(256)
void gemm64(const void* __restrict__ A0, const void* __restrict__ A1, const void* __restrict__ A2,
            const void* __restrict__ Wp0, const void* __restrict__ Wp1, const void* __restrict__ Wp2,
            const float* __restrict__ bia0, const float* __restrict__ bia1, const float* __restrict__ bia2,
            void* __restrict__ C0, void* __restrict__ C1, void* __restrict__ C2,
            const int N, const int K)
{
    constexpr int BM = 64, BN = 64, BK = 64, LS = 72; // 144B row stride -> 2-way bank alias (free)
    __shared__ u16 As[2][BM * LS];
    __shared__ u16 Bs[2][BN * LS];

    const int z = blockIdx.z;
    const void*  A     = (z == 0) ? A0 : (z == 1) ? A1 : A2;
    const void*  W     = (z == 0) ? Wp0 : (z == 1) ? Wp1 : Wp2;
    const float* bias1 = (z == 0) ? bia0 : (z == 1) ? bia1 : bia2;
    void*        Cout  = (z == 0) ? C0 : (z == 1) ? C1 : C2;

    const int tid  = threadIdx.x;
    const int wave = tid >> 6, lane = tid & 63;
    const int wm = wave >> 1, wn = wave & 1;
    const int r = lane & 15, q = lane >> 4;

    const int lin = blockIdx.y * 16 + blockIdx.x;
    const int mti = (lin & 7) | ((lin >> 7) << 3);
    const int nti = (lin >> 3) & 15;
    const int m0 = mti * BM, n0 = nti * BN;

    floatx4 acc[2][2];
    const floatx4 zf = {0.f, 0.f, 0.f, 0.f};
    #pragma unroll
    for (int a = 0; a < 2; a++)
        #pragma unroll
        for (int b = 0; b < 2; b++) acc[a][b] = zf;

    const int row0 = tid >> 3, kc = (tid & 7) << 3, row1 = row0 + 32;
    const size_t aOff0 = (size_t)(m0 + row0) * K + kc;
    const size_t aOff1 = (size_t)(m0 + row1) * K + kc;
    const size_t wOff0 = (size_t)(n0 + row0) * K + kc;
    const size_t wOff1 = (size_t)(n0 + row1) * K + kc;

    int4 av0 = ld8<AF32>(A, aOff0);
    int4 av1 = ld8<AF32>(A, aOff1);
    int4 bv0 = ld8<WF32>(W, wOff0);
    int4 bv1 = ld8<WF32>(W, wOff1);

    int p = 0;
    for (int kb = 0; kb < K; kb += BK) {
        *(int4*)&As[p][row0 * LS + kc] = av0;
        *(int4*)&As[p][row1 * LS + kc] = av1;
        *(int4*)&Bs[p][row0 * LS + kc] = bv0;
        *(int4*)&Bs[p][row1 * LS + kc] = bv1;
        __syncthreads();
        if (kb + BK < K) {
            av0 = ld8<AF32>(A, aOff0 + kb + BK);
            av1 = ld8<AF32>(A, aOff1 + kb + BK);
            bv0 = ld8<WF32>(W, wOff0 + kb + BK);
            bv1 = ld8<WF32>(W, wOff1 + kb + BK);
        }
        bf16x8 af[2][2], bfr[2][2];
        #pragma unroll
        for (int ks = 0; ks < 2; ks++)
            #pragma unroll
            for (int t = 0; t < 2; t++) {
                af[ks][t]  = *(const bf16x8*)&As[p][(wm * 32 + t * 16 + r) * LS + ks * 32 + q * 8];
                bfr[ks][t] = *(const bf16x8*)&Bs[p][(wn * 32 + t * 16 + r) * LS + ks * 32 + q * 8];
            }
        #pragma unroll
        for (int ks = 0; ks < 2; ks++)
            #pragma unroll
            for (int mt = 0; mt < 2; mt++)
                #pragma unroll
                for (int nt = 0; nt < 2; nt++)
                    acc[mt][nt] = __builtin_amdgcn_mfma_f32_16x16x32_bf16(af[ks][mt], bfr[ks][nt], acc[mt][nt], 0, 0, 0);
        p ^= 1;
    }

    #pragma unroll
    for (int mt = 0; mt < 2; mt++)
        #pragma unroll
        for (int nt = 0; nt < 2; nt++) {
            const int col  = n0 + wn * 32 + nt * 16 + r;
            const int rowb = m0 + wm * 32 + mt * 16 + q * 4;
            const float bb = bias1 ? bias1[col] : 0.f;
            #pragma unroll
            for (int i = 0; i < 4; i++) {
                float v = acc[mt][nt][i] + bb;
                if (ACT == 1) v = fmaxf(v, 0.f);
                if (OUT_F32) ((float*)Cout)[(size_t)(rowb + i) * N + col] = v;
                else ((u16*)Cout)[(size_t)(rowb + i) * N + col] = f2b(v);
            }
        }
}

// ---------------- persistent RNN: all 64 steps, one launch, manual grid barrier ----------------
// Grid MUST be (16,32) = 512 blocks (capacity: 37 KB LDS -> 4 blocks/CU, need 2 -> co-residency safe).
__global__ __launch_bounds__(256)
void rnn_persistent(const u16* __restrict__ hx0, u16* __restrict__ hx1,
                    const u16* __restrict__ Wsum, const u16* __restrict__ Whh,
                    const float* __restrict__ b_ih, const float* __restrict__ b_hh,
                    const float* __restrict__ pre_xh, const float* __restrict__ pre_xm,
                    const float* __restrict__ pre_xl,
                    const float* __restrict__ Wact, float* __restrict__ logits,
                    float* __restrict__ hx_out, unsigned* __restrict__ bar)
{
    constexpr int BM = 64, BN = 64, BK = 64, LS = 72;
    constexpr int K = H_DIM, N = H_DIM;
    __shared__ u16 As[2][BM * LS];
    __shared__ u16 Bs[2][BN * LS];

    const int tid  = threadIdx.x;
    const int wave = tid >> 6, lane = tid & 63;
    const int wm = wave >> 1, wn = wave & 1;
    const int r = lane & 15, q = lane >> 4;

    const int lin = blockIdx.y * 16 + blockIdx.x;
    const int mti = (lin & 7) | ((lin >> 7) << 3);
    const int nti = (lin >> 3) & 15;
    const int m0 = mti * BM, n0 = nti * BN;

    const int row0 = tid >> 3, kc = (tid & 7) << 3, row1 = row0 + 32;
    const size_t aOff0 = (size_t)(m0 + row0) * K + kc;
    const size_t aOff1 = (size_t)(m0 + row1) * K + kc;
    const size_t wOff0 = (size_t)(n0 + row0) * K + kc;
    const size_t wOff1 = (size_t)(n0 + row1) * K + kc;

    // per-column constants (wave-tile cols)
    float bih[2], bhh[2], wa[2];
    #pragma unroll
    for (int nt = 0; nt < 2; nt++) {
        const int col = n0 + wn * 32 + nt * 16 + r;
        bih[nt] = b_ih[col]; bhh[nt] = b_hh[col]; wa[nt] = Wact[col];
    }

    const u16* bufs[2] = {hx0, hx1};

    for (int s = 0; s < NSTEP; s++) {
        const bool special = (s == 15 || s == 21 || s == 37 || s == 42 || s == 58);
        const u16* Ap = bufs[s & 1];
        const u16* Wp = special ? Whh : Wsum;
        const float* pre = (s == 15) ? pre_xh
                          : (s == 21 || s == 37) ? pre_xm
                          : (s == 42 || s == 58) ? pre_xl : nullptr;

        floatx4 acc[2][2];
        const floatx4 zf = {0.f, 0.f, 0.f, 0.f};
        #pragma unroll
        for (int a = 0; a < 2; a++)
            #pragma unroll
            for (int b = 0; b < 2; b++) acc[a][b] = zf;

        int4 av0 = *(const int4*)(Ap + aOff0);
        int4 av1 = *(const int4*)(Ap + aOff1);
        int4 bv0 = *(const int4*)(Wp + wOff0);
        int4 bv1 = *(const int4*)(Wp + wOff1);

        int p = 0;
        for (int kb = 0; kb < K; kb += BK) {
            *(int4*)&As[p][row0 * LS + kc] = av0;
            *(int4*)&As[p][row1 * LS + kc] = av1;
            *(int4*)&Bs[p][row0 * LS + kc] = bv0;
            *(int4*)&Bs[p][row1 * LS + kc] = bv1;
            __syncthreads();
            if (kb + BK < K) {
                av0 = *(const int4*)(Ap + aOff0 + kb + BK);
                av1 = *(const int4*)(Ap + aOff1 + kb + BK);
                bv0 = *(const int4*)(Wp + wOff0 + kb + BK);
                bv1 = *(const int4*)(Wp + wOff1 + kb + BK);
            }
            bf16x8 af[2][2], bfr[2][2];
            #pragma unroll
            for (int ks = 0; ks < 2; ks++)
                #pragma unroll
                for (int t = 0; t < 2; t++) {
                    af[ks][t]  = *(const bf16x8*)&As[p][(wm * 32 + t * 16 + r) * LS + ks * 32 + q * 8];
                    bfr[ks][t] = *(const bf16x8*)&Bs[p][(wn * 32 + t * 16 + r) * LS + ks * 32 + q * 8];
                }
            #pragma unroll
            for (int ks = 0; ks < 2; ks++)
                #pragma unroll
                for (int mt = 0; mt < 2; mt++)
                    #pragma unroll
                    for (int nt = 0; nt < 2; nt++)
                        acc[mt][nt] = __builtin_amdgcn_mfma_f32_16x16x32_bf16(af[ks][mt], bfr[ks][nt], acc[mt][nt], 0, 0, 0);
            p ^= 1;
        }

        // epilogue: v = tanh(acc + bias (+pre)); write hx'; fused actor partial
        u16* dst = const_cast<u16*>(bufs[(s + 1) & 1]);
        #pragma unroll
        for (int mt = 0; mt < 2; mt++)
            #pragma unroll
            for (int nt = 0; nt < 2; nt++) {
                const int col  = n0 + wn * 32 + nt * 16 + r;
                const int rowb = m0 + wm * 32 + mt * 16 + q * 4;
                const float bb = special ? bhh[nt] : (bih[nt] + bhh[nt]);
                #pragma unroll
                for (int i = 0; i < 4; i++) {
                    float v = acc[mt][nt][i] + bb;
                    if (pre) v += pre[(size_t)(rowb + i) * N + col];
                    v = fast_tanh(v);
                    if (s == NSTEP - 1) hx_out[(size_t)(rowb + i) * N + col] = v;
                    else dst[(size_t)(rowb + i) * N + col] = f2b(v);
                    acc[mt][nt][i] = v;
                }
            }
        #pragma unroll
        for (int mt = 0; mt < 2; mt++)
            #pragma unroll
            for (int i = 0; i < 4; i++) {
                float sv = acc[mt][0][i] * wa[0] + acc[mt][1][i] * wa[1];
                sv += __shfl_xor(sv, 1);
                sv += __shfl_xor(sv, 2);
                sv += __shfl_xor(sv, 4);
                sv += __shfl_xor(sv, 8);
                if (r == 0)
                    atomicAdd(&logits[(size_t)s * B_DIM + m0 + wm * 32 + mt * 16 + q * 4 + i], sv);
            }

        if (s == NSTEP - 1) break;  // kernel end flushes; sigmoid kernel follows

        // ---- grid barrier (two-level: 8 sub-counters -> 1 global) ----
        __threadfence();          // release own hx' stores agent-wide (cross-XCD)
        __syncthreads();          // all waves of block fenced before arrival
        if (tid == 0) {
            unsigned* bs = bar + s * 9;
            unsigned prev = __hip_atomic_fetch_add(&bs[lin & 7], 1u, __ATOMIC_ACQ_REL, __HIP_MEMORY_SCOPE_AGENT);
            if (prev == 63u)
                __hip_atomic_fetch_add(&bs[8], 1u, __ATOMIC_ACQ_REL, __HIP_MEMORY_SCOPE_AGENT);
            while (__hip_atomic_load(&bs[8], __ATOMIC_RELAXED, __HIP_MEMORY_SCOPE_AGENT) < 8u)
                __builtin_amdgcn_s_sleep(2);
        }
        __syncthreads();
        __threadfence();          // acquire: see other blocks' hx' before next step's loads
    }
}

// fp32 -> bf16 bulk convert, z selects tensor; n elements (divisible by 8)
__global__ void convert_bf16(const float* __restrict__ s0, const float* __restrict__ s1,
                             const float* __restrict__ s2,
                             u16* __restrict__ d0, u16* __restrict__ d1, u16* __restrict__ d2,
                             int n)
{
    const int z = blockIdx.z;
    const float* s = (z == 0) ? s0 : (z == 1) ? s1 : s2;
    u16* d = (z == 0) ? d0 : (z == 1) ? d1 : d2;
    int i = (blockIdx.x * 256 + threadIdx.x) * 8;
    if (i < n) {
        float4 lo = *(const float4*)(s + i);
        float4 hi = *(const float4*)(s + i + 4);
        union { u16 h[8]; int4 v; } rr;
        rr.h[0] = f2b(lo.x); rr.h[1] = f2b(lo.y); rr.h[2] = f2b(lo.z); rr.h[3] = f2b(lo.w);
        rr.h[4] = f2b(hi.x); rr.h[5] = f2b(hi.y); rr.h[6] = f2b(hi.z); rr.h[7] = f2b(hi.w);
        *(int4*)(d + i) = rr.v;
    }
}

// Wsum = bf16(W_ih+W_hh), Whhb = bf16(W_hh), Wihb = bf16(W_ih)
__global__ void prep_w(const float* __restrict__ Wih, const float* __restrict__ Whh,
                       u16* __restrict__ Wsum, u16* __restrict__ Whhb, u16* __restrict__ Wihb, int n) {
    int i = blockIdx.x * 256 + threadIdx.x;
    if (i < n) {
        float a = Wih[i], b = Whh[i];
        Wsum[i] = f2b(a + b);
        Whhb[i] = f2b(b);
        Wihb[i] = f2b(a);
    }
}

__global__ void sigmoid_kernel(const float* __restrict__ logits, const float* __restrict__ b_act,
                               float* __restrict__ out, int n) {
    int i = blockIdx.x * 256 + threadIdx.x;
    if (i < n) {
        float zv = logits[i] + b_act[0];
        out[i] = 1.0f / (1.0f + __expf(-zv));
    }
}

extern "C" void kernel_launch(void* const* d_in, const int* in_sizes, int n_in,
                              void* d_out, int out_size, void* d_ws, size_t ws_size,
                              hipStream_t stream) {
    (void)in_sizes; (void)n_in; (void)out_size; (void)ws_size;
    const int Bn = B_DIM, F = F_DIM, H = H_DIM;

    const float* xin[3] = {(const float*)d_in[0], (const float*)d_in[1], (const float*)d_in[2]};
    const float* W1[3]  = {(const float*)d_in[3], (const float*)d_in[7], (const float*)d_in[11]};
    const float* b1[3]  = {(const float*)d_in[4], (const float*)d_in[8], (const float*)d_in[12]};
    const float* W2[3]  = {(const float*)d_in[5], (const float*)d_in[9], (const float*)d_in[13]};
    const float* b2[3]  = {(const float*)d_in[6], (const float*)d_in[10], (const float*)d_in[14]};
    const float* W_ih   = (const float*)d_in[15];
    const float* W_hh   = (const float*)d_in[16];
    const float* b_ih   = (const float*)d_in[17];
    const float* b_hh   = (const float*)d_in[18];
    const float* W_act  = (const float*)d_in[19];
    const float* b_act  = (const float*)d_in[20];

    // ws layout (phased overlaps; peak 47 MB, proven budget >= 48.5 MB)
    const size_t MB = 1024 * 1024;
    char* ws = (char*)d_ws;
    u16*   xl     = (u16*)(ws + 0 * MB);
    u16*   xm     = (u16*)(ws + 4 * MB);
    u16*   xh     = (u16*)(ws + 8 * MB);    // hx ping (hx0)
    u16*   hxB    = (u16*)(ws + 12 * MB);   // hx pong (hx1)
    u16*   Wsum   = (u16*)(ws + 16 * MB);
    u16*   Whhb   = (u16*)(ws + 18 * MB);
    u16*   Wihb   = (u16*)(ws + 20 * MB);
    u16*   h1a    = (u16*)(ws + 22 * MB);   // live fc1 -> fc2
    u16*   h1b    = (u16*)(ws + 26 * MB);
    u16*   h1c    = (u16*)(ws + 30 * MB);
    u16*   Wtmp   = (u16*)(ws + 34 * MB);   // 8 MB: per-branch W1 bf16; later W2 bf16 x3 (6 MB)
    float* pre_xh = (float*)(ws + 22 * MB); // written after fc2 (h1 dead)
    float* pre_xm = (float*)(ws + 30 * MB); // overlaps h1c + Wtmp head (dead by then)
    float* pre_xl = (float*)(ws + 38 * MB);
    float* logits = (float*)(ws + 46 * MB);                    // 512 KB
    unsigned* bar = (unsigned*)(ws + 46 * MB + 512 * 1024);    // 64*9 u32

    dim3 blk(256);
    dim3 gridH(16, 32, 1);
    dim3 grid3(16, 32, 3);

    (void)hipMemsetAsync(logits, 0, 512 * 1024 + 4096, stream);
    prep_w<<<dim3((H * H + 255) / 256), blk, 0, stream>>>(W_ih, W_hh, Wsum, Whhb, Wihb, H * H);

    // fc1 per branch: convert W1 -> bf16 (8 MB scratch), then GEMM (A stays fp32-fused)
    u16* h1[3] = {h1a, h1b, h1c};
    const int nW1 = H * F;  // 4.19M
    for (int m = 0; m < 3; m++) {
        convert_bf16<<<dim3((nW1 / 8 + 255) / 256, 1, 1), blk, 0, stream>>>(
            W1[m], nullptr, nullptr, Wtmp, nullptr, nullptr, nW1);
        gemm64<1,0,1,0><<<gridH, blk, 0, stream>>>(
            xin[m], nullptr, nullptr, Wtmp, nullptr, nullptr, b1[m], nullptr, nullptr,
            h1[m], nullptr, nullptr, H, F);
    }
    // fc2: convert W2 x3 (6 MB into Wtmp), batched GEMM
    const int nW2 = H * H;
    u16* W2b[3] = {Wtmp, Wtmp + nW2, Wtmp + 2 * nW2};
    convert_bf16<<<dim3((nW2 / 8 + 255) / 256, 1, 3), blk, 0, stream>>>(
        W2[0], W2[1], W2[2], W2b[0], W2b[1], W2b[2], nW2);
    gemm64<0,0,1,0><<<grid3, blk, 0, stream>>>(
        h1a, h1b, h1c, W2b[0], W2b[1], W2b[2], b2[0], b2[1], b2[2],
        xl, xm, xh, H, H);
    // pre (batched): pre_* = {xh,xm,xl} @ W_ih^T + b_ih (fp32 out)
    gemm64<0,0,0,1><<<grid3, blk, 0, stream>>>(
        xh, xm, xl, Wihb, Wihb, Wihb, b_ih, b_ih, b_ih,
        pre_xh, pre_xm, pre_xl, H, H);

    // persistent RNN: 64 steps, one launch
    float* hx_out = (float*)d_out + (size_t)NSTEP * Bn;
    rnn_persistent<<<gridH, blk, 0, stream>>>(
        xh, hxB, Wsum, Whhb, b_ih, b_hh, pre_xh, pre_xm, pre_xl,
        W_act, logits, hx_out, bar);

    sigmoid_kernel<<<dim3((NSTEP * Bn + 255) / 256), blk, 0, stream>>>(
        logits, b_act, (float*)d_out, NSTEP * Bn);
}

// Round 6
// 1360.094 us; speedup vs baseline: 4.7225x; 4.7225x over previous
//
#include <hip/hip_runtime.h>
#include <hip/hip_bf16.h>

typedef unsigned short u16;
typedef short bf16x8 __attribute__((ext_vector_type(8)));   // 8 bf16 (4 VGPRs) MFMA frag
typedef float floatx4 __attribute__((ext_vector_type(4)));  // MFMA acc

#define B_DIM 2048
#define F_DIM 4096
#define H_DIM 1024
#define NSTEP 64

__device__ __forceinline__ float fast_tanh(float x) {
    return 1.0f - 2.0f / (__expf(2.0f * x) + 1.0f);
}

__device__ __forceinline__ u16 f2b(float x) {  // fp32 -> bf16 RNE
    union { float f; unsigned u; } v; v.f = x;
    unsigned r = v.u + 0x7FFFu + ((v.u >> 16) & 1u);
    return (u16)(r >> 16);
}

template<int F32>
__device__ __forceinline__ int4 ld8(const void* base, size_t elemOff) {
    if constexpr (F32) {
        const float* p = (const float*)base + elemOff;
        float4 lo = *(const float4*)p;
        float4 hi = *(const float4*)(p + 4);
        union { u16 h[8]; int4 v; } rr;
        rr.h[0] = f2b(lo.x); rr.h[1] = f2b(lo.y); rr.h[2] = f2b(lo.z); rr.h[3] = f2b(lo.w);
        rr.h[4] = f2b(hi.x); rr.h[5] = f2b(hi.y); rr.h[6] = f2b(hi.z); rr.h[7] = f2b(hi.w);
        return rr.v;
    } else {
        return *(const int4*)((const u16*)base + elemOff);
    }
}

// ---------------- batched/selector GEMM for the parallel (MLP/pre) phase ----------------
// C[z] = act(A[z] @ W[z]^T + bias1[z]); grid must be (16, 32, z). BM=BN=BK=64, 256 thr.
template<int AF32, int WF32, int ACT, int OUT_F32>
__global__ __launch_bounds__(256)
void gemm64(const void* __restrict__ A0, const void* __restrict__ A1, const void* __restrict__ A2,
            const void* __restrict__ Wp0, const void* __restrict__ Wp1, const void* __restrict__ Wp2,
            const float* __restrict__ bia0, const float* __restrict__ bia1, const float* __restrict__ bia2,
            void* __restrict__ C0, void* __restrict__ C1, void* __restrict__ C2,
            const int N, const int K)
{
    constexpr int BM = 64, BN = 64, BK = 64, LS = 72;
    __shared__ u16 As[2][BM * LS];
    __shared__ u16 Bs[2][BN * LS];

    const int z = blockIdx.z;
    const void*  A     = (z == 0) ? A0 : (z == 1) ? A1 : A2;
    const void*  W     = (z == 0) ? Wp0 : (z == 1) ? Wp1 : Wp2;
    const float* bias1 = (z == 0) ? bia0 : (z == 1) ? bia1 : bia2;
    void*        Cout  = (z == 0) ? C0 : (z == 1) ? C1 : C2;

    const int tid  = threadIdx.x;
    const int wave = tid >> 6, lane = tid & 63;
    const int wm = wave >> 1, wn = wave & 1;
    const int r = lane & 15, q = lane >> 4;

    const int lin = blockIdx.y * 16 + blockIdx.x;
    const int mti = (lin & 7) | ((lin >> 7) << 3);
    const int nti = (lin >> 3) & 15;
    const int m0 = mti * BM, n0 = nti * BN;

    floatx4 acc[2][2];
    const floatx4 zf = {0.f, 0.f, 0.f, 0.f};
    #pragma unroll
    for (int a = 0; a < 2; a++)
        #pragma unroll
        for (int b = 0; b < 2; b++) acc[a][b] = zf;

    const int row0 = tid >> 3, kc = (tid & 7) << 3, row1 = row0 + 32;
    const size_t aOff0 = (size_t)(m0 + row0) * K + kc;
    const size_t aOff1 = (size_t)(m0 + row1) * K + kc;
    const size_t wOff0 = (size_t)(n0 + row0) * K + kc;
    const size_t wOff1 = (size_t)(n0 + row1) * K + kc;

    int4 av0 = ld8<AF32>(A, aOff0);
    int4 av1 = ld8<AF32>(A, aOff1);
    int4 bv0 = ld8<WF32>(W, wOff0);
    int4 bv1 = ld8<WF32>(W, wOff1);

    int p = 0;
    for (int kb = 0; kb < K; kb += BK) {
        *(int4*)&As[p][row0 * LS + kc] = av0;
        *(int4*)&As[p][row1 * LS + kc] = av1;
        *(int4*)&Bs[p][row0 * LS + kc] = bv0;
        *(int4*)&Bs[p][row1 * LS + kc] = bv1;
        __syncthreads();
        if (kb + BK < K) {
            av0 = ld8<AF32>(A, aOff0 + kb + BK);
            av1 = ld8<AF32>(A, aOff1 + kb + BK);
            bv0 = ld8<WF32>(W, wOff0 + kb + BK);
            bv1 = ld8<WF32>(W, wOff1 + kb + BK);
        }
        bf16x8 af[2][2], bfr[2][2];
        #pragma unroll
        for (int ks = 0; ks < 2; ks++)
            #pragma unroll
            for (int t = 0; t < 2; t++) {
                af[ks][t]  = *(const bf16x8*)&As[p][(wm * 32 + t * 16 + r) * LS + ks * 32 + q * 8];
                bfr[ks][t] = *(const bf16x8*)&Bs[p][(wn * 32 + t * 16 + r) * LS + ks * 32 + q * 8];
            }
        #pragma unroll
        for (int ks = 0; ks < 2; ks++)
            #pragma unroll
            for (int mt = 0; mt < 2; mt++)
                #pragma unroll
                for (int nt = 0; nt < 2; nt++)
                    acc[mt][nt] = __builtin_amdgcn_mfma_f32_16x16x32_bf16(af[ks][mt], bfr[ks][nt], acc[mt][nt], 0, 0, 0);
        p ^= 1;
    }

    #pragma unroll
    for (int mt = 0; mt < 2; mt++)
        #pragma unroll
        for (int nt = 0; nt < 2; nt++) {
            const int col  = n0 + wn * 32 + nt * 16 + r;
            const int rowb = m0 + wm * 32 + mt * 16 + q * 4;
            const float bb = bias1 ? bias1[col] : 0.f;
            #pragma unroll
            for (int i = 0; i < 4; i++) {
                float v = acc[mt][nt][i] + bb;
                if (ACT == 1) v = fmaxf(v, 0.f);
                if (OUT_F32) ((float*)Cout)[(size_t)(rowb + i) * N + col] = v;
                else ((u16*)Cout)[(size_t)(rowb + i) * N + col] = f2b(v);
            }
        }
}

// ---------------- RNN step GEMM: 512 threads, BM=64 x BN=64, 16 waves/CU ----------------
// hx' = tanh(hx @ W^T + bias (+pre)); fused actor partial via LDS reduce + 64 atomics/block.
// Grid MUST be (16,32) = 512 blocks; 36.9 KB LDS -> 2 blocks/CU, 16 waves/CU.
// 8 waves: wm=wave>>2 (2) x wn=wave&3 (4); wave tile 32 rows x 16 cols (2x1 MFMA frags).
template<int HAS_PRE, int LAST>
__global__ __launch_bounds__(512)
void gemm_step(const u16* __restrict__ A, const u16* __restrict__ W,
               const float* __restrict__ bias, const float* __restrict__ pre,
               void* __restrict__ Cout, const float* __restrict__ Wact,
               float* __restrict__ logits)
{
    constexpr int BM = 64, BN = 64, BK = 64, LS = 72, K = H_DIM, N = H_DIM;
    __shared__ u16 As[2][BM * LS];
    __shared__ u16 Bs[2][BN * LS];

    const int tid  = threadIdx.x;
    const int wave = tid >> 6, lane = tid & 63;
    const int wm = wave >> 2, wn = wave & 3;
    const int r = lane & 15, q = lane >> 4;

    const int lin = blockIdx.y * 16 + blockIdx.x;
    const int mti = (lin & 7) | ((lin >> 7) << 3);   // XCD-pinned m-tiles
    const int nti = (lin >> 3) & 15;
    const int m0 = mti * BM, n0 = nti * BN;

    const int row = tid >> 3, kc = (tid & 7) << 3;   // 1 A-chunk + 1 B-chunk per thread
    const size_t aOff = (size_t)(m0 + row) * K + kc;
    const size_t wOff = (size_t)(n0 + row) * K + kc;

    floatx4 acc[2];
    const floatx4 zf = {0.f, 0.f, 0.f, 0.f};
    acc[0] = zf; acc[1] = zf;

    int4 av = *(const int4*)(A + aOff);
    int4 bv = *(const int4*)(W + wOff);

    int p = 0;
    for (int kb = 0; kb < K; kb += BK) {
        *(int4*)&As[p][row * LS + kc] = av;
        *(int4*)&Bs[p][row * LS + kc] = bv;
        __syncthreads();
        if (kb + BK < K) {
            av = *(const int4*)(A + aOff + kb + BK);
            bv = *(const int4*)(W + wOff + kb + BK);
        }
        bf16x8 af[2][2], bfr[2];
        #pragma unroll
        for (int ks = 0; ks < 2; ks++) {
            #pragma unroll
            for (int mt = 0; mt < 2; mt++)
                af[ks][mt] = *(const bf16x8*)&As[p][(wm * 32 + mt * 16 + r) * LS + ks * 32 + q * 8];
            bfr[ks] = *(const bf16x8*)&Bs[p][(wn * 16 + r) * LS + ks * 32 + q * 8];
        }
        #pragma unroll
        for (int ks = 0; ks < 2; ks++)
            #pragma unroll
            for (int mt = 0; mt < 2; mt++)
                acc[mt] = __builtin_amdgcn_mfma_f32_16x16x32_bf16(af[ks][mt], bfr[ks], acc[mt], 0, 0, 0);
        p ^= 1;
    }

    // Epilogue. C/D layout: row = q*4+i, col = r.
    const int col = n0 + wn * 16 + r;
    const float bb = bias[col];
    const float wa = Wact[col];
    #pragma unroll
    for (int mt = 0; mt < 2; mt++) {
        const int rowb = m0 + wm * 32 + mt * 16 + q * 4;
        #pragma unroll
        for (int i = 0; i < 4; i++) {
            float v = acc[mt][i] + bb;
            if (HAS_PRE) v += pre[(size_t)(rowb + i) * N + col];
            v = fast_tanh(v);
            if (LAST) ((float*)Cout)[(size_t)(rowb + i) * N + col] = v;
            else ((u16*)Cout)[(size_t)(rowb + i) * N + col] = f2b(v);
            acc[mt][i] = v;
        }
    }

    // Actor head: per-wave shuffle-reduce over 16 cols -> LDS [wn][64 rows] -> 64 atomics/block
    __syncthreads();                  // all LDS frag reads done; reuse As as scratch
    float* sc = (float*)As;           // 4 x 64 floats
    #pragma unroll
    for (int mt = 0; mt < 2; mt++)
        #pragma unroll
        for (int i = 0; i < 4; i++) {
            float s = acc[mt][i] * wa;
            s += __shfl_xor(s, 1);
            s += __shfl_xor(s, 2);
            s += __shfl_xor(s, 4);
            s += __shfl_xor(s, 8);
            if (r == 0) sc[wn * 64 + wm * 32 + mt * 16 + q * 4 + i] = s;
        }
    __syncthreads();
    if (tid < 64) {
        float s = sc[tid] + sc[64 + tid] + sc[128 + tid] + sc[192 + tid];
        atomicAdd(&logits[m0 + tid], s);
    }
}

// fp32 -> bf16 bulk convert, z selects tensor
__global__ void convert_bf16(const float* __restrict__ s0, const float* __restrict__ s1,
                             const float* __restrict__ s2,
                             u16* __restrict__ d0, u16* __restrict__ d1, u16* __restrict__ d2,
                             int n)
{
    const int z = blockIdx.z;
    const float* s = (z == 0) ? s0 : (z == 1) ? s1 : s2;
    u16* d = (z == 0) ? d0 : (z == 1) ? d1 : d2;
    int i = (blockIdx.x * 256 + threadIdx.x) * 8;
    if (i < n) {
        float4 lo = *(const float4*)(s + i);
        float4 hi = *(const float4*)(s + i + 4);
        union { u16 h[8]; int4 v; } rr;
        rr.h[0] = f2b(lo.x); rr.h[1] = f2b(lo.y); rr.h[2] = f2b(lo.z); rr.h[3] = f2b(lo.w);
        rr.h[4] = f2b(hi.x); rr.h[5] = f2b(hi.y); rr.h[6] = f2b(hi.z); rr.h[7] = f2b(hi.w);
        *(int4*)(d + i) = rr.v;
    }
}

// Wsum = bf16(W_ih+W_hh), Whhb = bf16(W_hh), Wihb = bf16(W_ih); bsum = b_ih + b_hh
__global__ void prep_w(const float* __restrict__ Wih, const float* __restrict__ Whh,
                       u16* __restrict__ Wsum, u16* __restrict__ Whhb, u16* __restrict__ Wihb,
                       const float* __restrict__ bih, const float* __restrict__ bhh,
                       float* __restrict__ bsum, int n) {
    int i = blockIdx.x * 256 + threadIdx.x;
    if (i < n) {
        float a = Wih[i], b = Whh[i];
        Wsum[i] = f2b(a + b);
        Whhb[i] = f2b(b);
        Wihb[i] = f2b(a);
    }
    if (i < H_DIM) bsum[i] = bih[i] + bhh[i];
}

__global__ void sigmoid_kernel(const float* __restrict__ logits, const float* __restrict__ b_act,
                               float* __restrict__ out, int n) {
    int i = blockIdx.x * 256 + threadIdx.x;
    if (i < n) {
        float zv = logits[i] + b_act[0];
        out[i] = 1.0f / (1.0f + __expf(-zv));
    }
}

extern "C" void kernel_launch(void* const* d_in, const int* in_sizes, int n_in,
                              void* d_out, int out_size, void* d_ws, size_t ws_size,
                              hipStream_t stream) {
    (void)in_sizes; (void)n_in; (void)out_size; (void)ws_size;
    const int Bn = B_DIM, F = F_DIM, H = H_DIM;

    const float* xin[3] = {(const float*)d_in[0], (const float*)d_in[1], (const float*)d_in[2]};
    const float* W1[3]  = {(const float*)d_in[3], (const float*)d_in[7], (const float*)d_in[11]};
    const float* b1[3]  = {(const float*)d_in[4], (const float*)d_in[8], (const float*)d_in[12]};
    const float* W2[3]  = {(const float*)d_in[5], (const float*)d_in[9], (const float*)d_in[13]};
    const float* b2[3]  = {(const float*)d_in[6], (const float*)d_in[10], (const float*)d_in[14]};
    const float* W_ih   = (const float*)d_in[15];
    const float* W_hh   = (const float*)d_in[16];
    const float* b_ih   = (const float*)d_in[17];
    const float* b_hh   = (const float*)d_in[18];
    const float* W_act  = (const float*)d_in[19];
    const float* b_act  = (const float*)d_in[20];

    // ws layout (phased overlaps; peak ~47 MB)
    const size_t MB = 1024 * 1024;
    char* ws = (char*)d_ws;
    u16*   xl     = (u16*)(ws + 0 * MB);
    u16*   xm     = (u16*)(ws + 4 * MB);
    u16*   xh     = (u16*)(ws + 8 * MB);    // hx ping
    u16*   hxB    = (u16*)(ws + 12 * MB);   // hx pong
    u16*   Wsum   = (u16*)(ws + 16 * MB);
    u16*   Whhb   = (u16*)(ws + 18 * MB);
    u16*   Wihb   = (u16*)(ws + 20 * MB);
    u16*   h1a    = (u16*)(ws + 22 * MB);   // live fc1 -> fc2
    u16*   h1b    = (u16*)(ws + 26 * MB);
    u16*   h1c    = (u16*)(ws + 30 * MB);
    u16*   Wtmp   = (u16*)(ws + 34 * MB);   // 8 MB scratch: W1 bf16 per branch; later W2 bf16 x3
    float* pre_xh = (float*)(ws + 22 * MB); // written after fc2 (h1 dead)
    float* pre_xm = (float*)(ws + 30 * MB); // overlaps h1c+Wtmp head (dead by then)
    float* pre_xl = (float*)(ws + 38 * MB);
    float* logits = (float*)(ws + 46 * MB);                  // 512 KB
    float* bsum   = (float*)(ws + 46 * MB + 512 * 1024);     // 4 KB

    dim3 blk(256);
    dim3 blkS(512);
    dim3 gridH(16, 32, 1);
    dim3 grid3(16, 32, 3);

    (void)hipMemsetAsync(logits, 0, (size_t)NSTEP * Bn * sizeof(float), stream);
    prep_w<<<dim3((H * H + 255) / 256), blk, 0, stream>>>(W_ih, W_hh, Wsum, Whhb, Wihb,
                                                          b_ih, b_hh, bsum, H * H);

    // fc1 per branch: convert W1 -> bf16 (8 MB scratch), then GEMM (A fp32-fused)
    u16* h1[3] = {h1a, h1b, h1c};
    const int nW1 = H * F;
    for (int m = 0; m < 3; m++) {
        convert_bf16<<<dim3((nW1 / 8 + 255) / 256, 1, 1), blk, 0, stream>>>(
            W1[m], nullptr, nullptr, Wtmp, nullptr, nullptr, nW1);
        gemm64<1,0,1,0><<<gridH, blk, 0, stream>>>(
            xin[m], nullptr, nullptr, Wtmp, nullptr, nullptr, b1[m], nullptr, nullptr,
            h1[m], nullptr, nullptr, H, F);
    }
    // fc2: convert W2 x3, batched GEMM
    const int nW2 = H * H;
    u16* W2b[3] = {Wtmp, Wtmp + nW2, Wtmp + 2 * nW2};
    convert_bf16<<<dim3((nW2 / 8 + 255) / 256, 1, 3), blk, 0, stream>>>(
        W2[0], W2[1], W2[2], W2b[0], W2b[1], W2b[2], nW2);
    gemm64<0,0,1,0><<<grid3, blk, 0, stream>>>(
        h1a, h1b, h1c, W2b[0], W2b[1], W2b[2], b2[0], b2[1], b2[2],
        xl, xm, xh, H, H);
    // pre (batched): pre_* = {xh,xm,xl} @ W_ih^T + b_ih (fp32 out)
    gemm64<0,0,0,1><<<grid3, blk, 0, stream>>>(
        xh, xm, xl, Wihb, Wihb, Wihb, b_ih, b_ih, b_ih,
        pre_xh, pre_xm, pre_xl, H, H);

    // sequential RNN: special steps {15:xh, 21:xm, 37:xm, 42:xl, 58:xl}
    u16* hx = xh;
    u16* nxt = hxB;
    for (int step = 0; step < NSTEP; step++) {
        const float* pre = nullptr;
        if (step == 15) pre = pre_xh;
        else if (step == 21 || step == 37) pre = pre_xm;
        else if (step == 42 || step == 58) pre = pre_xl;
        float* lg = logits + (size_t)step * Bn;
        if (step == NSTEP - 1) {
            float* outf = (float*)d_out + (size_t)NSTEP * Bn;
            gemm_step<0,1><<<gridH, blkS, 0, stream>>>(hx, Wsum, bsum, nullptr, outf, W_act, lg);
        } else if (pre) {
            gemm_step<1,0><<<gridH, blkS, 0, stream>>>(hx, Whhb, b_hh, pre, nxt, W_act, lg);
        } else {
            gemm_step<0,0><<<gridH, blkS, 0, stream>>>(hx, Wsum, bsum, nullptr, nxt, W_act, lg);
        }
        u16* t = hx; hx = nxt; nxt = t;
    }
    sigmoid_kernel<<<dim3((NSTEP * Bn + 255) / 256), blk, 0, stream>>>(
        logits, b_act, (float*)d_out, NSTEP * Bn);
}